// Round 13
// baseline (33.049 us; speedup 1.0000x reference)
//
#include <hip/hip_runtime.h>

// 4-level db4 wavedec ('symmetric'), composed-filter 2-stage version.
// x: [B=64, L=4096, C=32] f32. Out flat: cA4,cD4,cD3,cD2,cD1 each [B,C,len].
// lens: 4096 -> 2051 -> 1029 -> 518 -> 262.
// Key idea: cA1 and cA3 are not outputs -> skip them. Composed 22-tap filters
// compute {cD2,cA2} directly from x and {cD4,cA4} directly from cA2. Exact in
// the interior (margins make it exact wherever intermediate cA1/cA3 indices
// are in-range); <=4 boundary outputs per edge handled by explicit cascade
// fallback on a designated slot. 2 dependent stages, 3 barriers.
// Block = (batch, 4-ch group, tile of 33 cA4); 4096 blocks x 256 thr.

#define NT 256
#define NCHB 4

#define LPX 634  // bx pitch: x span <= 618 (+13 margins), == 2 mod 4
#define LB2 166  // b2 (cA2) pitch: span <= 150 (+13)
#define CDP1 266 // cd1 staging (owned span <= 264)
#define CDP2 134 // cd2 staging (<=132)
#define CDP3 70  // cd3 staging (<=66)
#define CDP4 34  // cd4 staging (<=33)
#define CAP4 34  // ca4 staging (<=33)

#define L0C 4096
#define L1C 2051
#define L2C 1029
#define L3C 518
#define L4C 262
#define SC 2048

#define OFF_CD4 (SC * L4C)
#define OFF_CD3 (2 * SC * L4C)
#define OFF_CD2 (OFF_CD3 + SC * L3C)
#define OFF_CD1 (OFF_CD2 + SC * L2C)

// db4 rec_lo (double) and derived correlation kernels.
constexpr double DLO[8] = {
    0.23037781330885523,  0.7148465705525415,  0.6308807679295904,
    -0.02798376941698385, -0.18703481171888114, 0.030841381835986965,
    0.032883011666982945, -0.010597401784997278};
constexpr double DHI[8] = {
    -0.010597401784997278, -0.032883011666982945, 0.030841381835986965,
    0.18703481171888114,  -0.02798376941698385,  -0.6308807679295904,
    0.7148465705525415,   -0.23037781330885523};

struct E22 { float a[22]; float d[22]; };
// Composed skip-level filters: out2[i] = sum_m F[m] * cA[2i-6+m],
// cA[j] = sum_k LO[k] * src[2j-6+k]  =>  src index 4i-18+u, u=2m+k in [0,21].
constexpr E22 make_e22() {
    E22 e{};
    double da[22] = {}, dd[22] = {};
    for (int m = 0; m < 8; ++m)
        for (int k = 0; k < 8; ++k) {
            da[2 * m + k] += DLO[m] * DLO[k];
            dd[2 * m + k] += DHI[m] * DLO[k];
        }
    for (int u = 0; u < 22; ++u) { e.a[u] = (float)da[u]; e.d[u] = (float)dd[u]; }
    return e;
}

__device__ __forceinline__ float dot8lo(const float* __restrict__ w) {
    constexpr float F[8] = {
        0.23037781330885523f,  0.7148465705525415f,  0.6308807679295904f,
        -0.02798376941698385f, -0.18703481171888114f, 0.030841381835986965f,
        0.032883011666982945f, -0.010597401784997278f};
    float s0 = F[0] * w[0];
    s0 = fmaf(F[1], w[1], s0); s0 = fmaf(F[2], w[2], s0); s0 = fmaf(F[3], w[3], s0);
    float s1 = F[4] * w[4];
    s1 = fmaf(F[5], w[5], s1); s1 = fmaf(F[6], w[6], s1); s1 = fmaf(F[7], w[7], s1);
    return s0 + s1;
}
__device__ __forceinline__ float dot8hi(const float* __restrict__ w) {
    constexpr float F[8] = {
        -0.010597401784997278f, -0.032883011666982945f, 0.030841381835986965f,
        0.18703481171888114f,  -0.02798376941698385f,  -0.6308807679295904f,
        0.7148465705525415f,   -0.23037781330885523f};
    float s0 = F[0] * w[0];
    s0 = fmaf(F[1], w[1], s0); s0 = fmaf(F[2], w[2], s0); s0 = fmaf(F[3], w[3], s0);
    float s1 = F[4] * w[4];
    s1 = fmaf(F[5], w[5], s1); s1 = fmaf(F[6], w[6], s1); s1 = fmaf(F[7], w[7], s1);
    return s0 + s1;
}

template <bool WA, bool WD>
__device__ __forceinline__ void dot22t(const float* __restrict__ w, float& a, float& d) {
    constexpr E22 E = make_e22();
    float a0 = 0.f, a1 = 0.f, d0 = 0.f, d1 = 0.f;
#pragma unroll
    for (int u = 0; u < 22; u += 2) {
        if constexpr (WA) a0 = fmaf(E.a[u], w[u], a0);
        if constexpr (WD) d0 = fmaf(E.d[u], w[u], d0);
    }
#pragma unroll
    for (int u = 1; u < 22; u += 2) {
        if constexpr (WA) a1 = fmaf(E.a[u], w[u], a1);
        if constexpr (WD) d1 = fmaf(E.d[u], w[u], d1);
    }
    if constexpr (WA) a = a0 + a1;
    if constexpr (WD) d = d0 + d1;
}

// 8-tap HI run: R outputs over [lo,hi) from windowed src row (sample t at word
// t - srclo + 6). Clamped-overlap remainder (pure function -> idempotent).
template <int R>
__device__ __forceinline__ void run8d(
    const float* __restrict__ src, int PS, int srclo,
    int lo, int hi,
    float* __restrict__ dbuf, int DP, int obase,
    int c, int slot) {
    int i0 = lo + slot * R;
    if (i0 >= hi) return;
    if (i0 > hi - R) i0 = hi - R;
    const float2* row2 = reinterpret_cast<const float2*>(src + c * PS);
    const int p = i0 - (srclo >> 1);  // word 2*i0 - srclo (even)
    float w[2 * R + 6];
#pragma unroll
    for (int j = 0; j < R + 3; ++j) {
        const float2 v = row2[p + j];
        w[2 * j] = v.x; w[2 * j + 1] = v.y;
    }
    float* drow = dbuf + c * DP - obase;
#pragma unroll
    for (int r = 0; r < R; ++r) drow[i0 + r] = dot8hi(&w[2 * r]);
}

// 22-tap run, staged outputs (d always; a optionally).
template <int R, bool WITH_A>
__device__ __forceinline__ void run22s(
    const float* __restrict__ src, int PS, int srclo,
    int lo, int hi,
    float* __restrict__ dbuf, int DP,
    float* __restrict__ abuf, int AP, int obase,
    int c, int slot) {
    int i0 = lo + slot * R;
    if (i0 >= hi) return;
    if (i0 > hi - R) i0 = hi - R;
    const float2* row2 = reinterpret_cast<const float2*>(src + c * PS);
    const int p = 2 * i0 - 6 - (srclo >> 1);  // word 4*i0-12-srclo (even)
    float w[4 * R + 18];
#pragma unroll
    for (int j = 0; j < 2 * R + 9; ++j) {
        const float2 v = row2[p + j];
        w[2 * j] = v.x; w[2 * j + 1] = v.y;
    }
    float* drow = dbuf + c * DP - obase;
#pragma unroll
    for (int r = 0; r < R; ++r) {
        float a, d;
        dot22t<WITH_A, true>(&w[4 * r], a, d);
        drow[i0 + r] = d;
        if constexpr (WITH_A) (abuf + c * AP - obase)[i0 + r] = a;
    }
}

// 22-tap run writing cA2 into windowed b2 row (+ reflection margins if MG).
template <int R, bool MG>
__device__ __forceinline__ void run22w(
    const float* __restrict__ src, int PS, int srclo,
    int lo, int hi,
    float* __restrict__ b2, int wlo,
    int c, int slot) {
    int i0 = lo + slot * R;
    if (i0 >= hi) return;
    if (i0 > hi - R) i0 = hi - R;
    const float2* row2 = reinterpret_cast<const float2*>(src + c * PS);
    const int p = 2 * i0 - 6 - (srclo >> 1);
    float w[4 * R + 18];
#pragma unroll
    for (int j = 0; j < 2 * R + 9; ++j) {
        const float2 v = row2[p + j];
        w[2 * j] = v.x; w[2 * j + 1] = v.y;
    }
    float* wr = b2 + c * LB2;
#pragma unroll
    for (int r = 0; r < R; ++r) {
        float a, dummy;
        dot22t<true, false>(&w[4 * r], a, dummy);
        const int i = i0 + r;
        wr[i - wlo + 6] = a;
        if constexpr (MG) {
            if (wlo == 0 && i < 6) wr[5 - i] = a;
            if (i >= L2C - 7) wr[(2 * L2C - 1 - i) - wlo + 6] = a;
        }
    }
}

// Dump staged rows to global: float2 LDS reads, coalesced dword stores.
__device__ __forceinline__ void dump_rows(
    const float* __restrict__ buf, int pitch,
    float* __restrict__ gbase, int rowLen, int ownLo, int ownHi, int tid) {
    const int span = ownHi - ownLo;
    const int n2 = span >> 1;
#pragma unroll
    for (int c2 = 0; c2 < NCHB; ++c2) {
        const float2* s2 = reinterpret_cast<const float2*>(buf + c2 * pitch);
        float* g = gbase + c2 * rowLen + ownLo;
        for (int k = tid; k < n2; k += NT) {
            const float2 v = s2[k];
            g[2 * k] = v.x;
            g[2 * k + 1] = v.y;
        }
        if ((span & 1) && tid == 0) g[span - 1] = buf[c2 * pitch + span - 1];
    }
}

template <bool MG>
__device__ __forceinline__ void cascade(
    const float* bx, float* b2,
    float* cd1, float* cd2, float* cd3, float* cd4, float* ca4,
    float* __restrict__ out, int sigB, int tile, int c, int slot, int tid,
    int lox, int lo2, int hi2, int lo4, int hi4) {
    // owned (exclusive, tile-partitioned) output ranges
    const int o1lo = tile ? 264 * tile - 34 : 0;
    const int o1hi = (tile == 7) ? L1C : 264 * tile + 230;
    const int o2lo = tile ? 132 * tile - 10 : 0;
    const int o2hi = (tile == 7) ? L2C : 132 * tile + 122;
    const int o3lo = tile ? 66 * tile - 2 : 0;
    const int o3hi = (tile == 7) ? L3C : 66 * tile + 64;

    // direct-valid clips (composed filter needs intermediate indices in-range)
    const int d2lo = MG ? max(o2lo, 3) : o2lo;
    const int d2hi = MG ? min(o2hi, 1025) : o2hi;
    const int a2lo = MG ? max(lo2, 3) : lo2;
    const int a2hi = MG ? min(hi2, 1025) : hi2;
    const int c4lo = MG ? max(lo4, 3) : lo4;
    const int c4hi = MG ? min(hi4, 259) : hi4;

    // ---- Stage A: everything reads bx only ----
    run8d<6>(bx, LPX, lox, o1lo, o1hi, cd1, CDP1, o1lo, c, slot);
    run22s<3, false>(bx, LPX, lox, d2lo, d2hi, cd2, CDP2, nullptr, 0, o2lo,
                     c, (slot + 44) & 63);
    run22w<3, MG>(bx, LPX, lox, a2lo, a2hi, b2, lo2, c, (slot + 32) & 63);
    if (MG && slot == 19) {
        // boundary cD2/cA2 via explicit cA1 cascade (reflect at L1C)
        const float* xr = bx + c * LPX + 6 - lox;  // xr[t] = x[t] (margins ok)
        float* wr = b2 + c * LB2;
        float* cd2row = cd2 + c * CDP2 - o2lo;
        const int ilo = (lo2 == 0) ? 0 : 1025;
        const int ihi = (lo2 == 0) ? 3 : L2C;
        for (int i = ilo; i < ihi; ++i) {
            float a = 0.f, d = 0.f;
#pragma unroll
            for (int m = 0; m < 8; ++m) {
                int j = 2 * i - 6 + m;
                j = (j < 0) ? -1 - j : ((j >= L1C) ? 2 * L1C - 1 - j : j);
                const float s = dot8lo(xr + 2 * j - 6);
                constexpr float FL[8] = {
                    0.23037781330885523f,  0.7148465705525415f,  0.6308807679295904f,
                    -0.02798376941698385f, -0.18703481171888114f, 0.030841381835986965f,
                    0.032883011666982945f, -0.010597401784997278f};
                constexpr float FH[8] = {
                    -0.010597401784997278f, -0.032883011666982945f, 0.030841381835986965f,
                    0.18703481171888114f,  -0.02798376941698385f,  -0.6308807679295904f,
                    0.7148465705525415f,   -0.23037781330885523f};
                a = fmaf(FL[m], s, a);
                d = fmaf(FH[m], s, d);
            }
            wr[i - lo2 + 6] = a;
            if (lo2 == 0 && i < 6) wr[5 - i] = a;
            if (i >= L2C - 7) wr[(2 * L2C - 1 - i) - lo2 + 6] = a;
            if (i >= o2lo && i < o2hi) cd2row[i] = d;
        }
    }
    __syncthreads();

    // ---- Stage B: dumps (VMEM) issued first, then compute from b2 ----
    dump_rows(cd1, CDP1, out + OFF_CD1 + sigB * L1C, L1C, o1lo, o1hi, tid);
    dump_rows(cd2, CDP2, out + OFF_CD2 + sigB * L2C, L2C, o2lo, o2hi, tid);
    run8d<2>(b2, LB2, lo2, o3lo, o3hi, cd3, CDP3, o3lo, c, slot);
    run22s<2, true>(b2, LB2, lo2, c4lo, c4hi, cd4, CDP4, ca4, CAP4, lo4,
                    c, (slot + 34) & 63);
    if (MG && slot == 63) {
        // boundary cD4/cA4 via explicit cA3 cascade (reflect at L3C)
        const float* a2 = b2 + c * LB2 + 6 - lo2;  // a2[t] = cA2[t] (margins ok)
        float* ca4row = ca4 + c * CAP4 - lo4;
        float* cd4row = cd4 + c * CDP4 - lo4;
        const int ilo = (lo4 == 0) ? 0 : 259;
        const int ihi = (lo4 == 0) ? 3 : L4C;
        for (int i = ilo; i < ihi; ++i) {
            float a = 0.f, d = 0.f;
#pragma unroll
            for (int m = 0; m < 8; ++m) {
                int j = 2 * i - 6 + m;
                j = (j < 0) ? -1 - j : ((j >= L3C) ? 2 * L3C - 1 - j : j);
                const float s = dot8lo(a2 + 2 * j - 6);
                constexpr float FL[8] = {
                    0.23037781330885523f,  0.7148465705525415f,  0.6308807679295904f,
                    -0.02798376941698385f, -0.18703481171888114f, 0.030841381835986965f,
                    0.032883011666982945f, -0.010597401784997278f};
                constexpr float FH[8] = {
                    -0.010597401784997278f, -0.032883011666982945f, 0.030841381835986965f,
                    0.18703481171888114f,  -0.02798376941698385f,  -0.6308807679295904f,
                    0.7148465705525415f,   -0.23037781330885523f};
                a = fmaf(FL[m], s, a);
                d = fmaf(FH[m], s, d);
            }
            ca4row[i] = a;
            cd4row[i] = d;
        }
    }
    __syncthreads();

    dump_rows(cd3, CDP3, out + OFF_CD3 + sigB * L3C, L3C, o3lo, o3hi, tid);
    dump_rows(cd4, CDP4, out + OFF_CD4 + sigB * L4C, L4C, lo4, hi4, tid);
    dump_rows(ca4, CAP4, out + sigB * L4C, L4C, lo4, hi4, tid);
}

__global__ __launch_bounds__(NT) void fused_dwt_kernel(
    const float* __restrict__ x, float* __restrict__ out) {
    __shared__ __align__(16) float bx[NCHB * LPX];
    __shared__ __align__(16) float b2[NCHB * LB2];
    __shared__ __align__(16) float cd1[NCHB * CDP1];
    __shared__ __align__(16) float cd2[NCHB * CDP2];
    __shared__ __align__(16) float cd3[NCHB * CDP3];
    __shared__ __align__(16) float cd4[NCHB * CDP4];
    __shared__ __align__(16) float ca4[NCHB * CAP4];

    // XCD swizzle: 4096 blocks = 8 XCDs x 512 contiguous works.
    const int bid = blockIdx.x;
    const int work = (bid & 7) * 512 + (bid >> 3);
    const int cg = work & 7;           // channel group 0..7 (4 ch each)
    const int tile = (work >> 3) & 7;  // cA4 tile 0..7
    const int b = work >> 6;           // batch 0..63

    const int tid = threadIdx.x;
    const int c = tid & 3;
    const int slot = tid >> 2;  // 0..63
    const int c0 = cg * 4;
    const int sigB = b * 32 + c0;

    const int lo4 = 33 * tile, hi4 = min(L4C, lo4 + 33);
    const int lo3 = max(0, 2 * lo4 - 6), hi3 = min(L3C, 2 * hi4);
    const int lo2 = max(0, 2 * lo3 - 6), hi2 = min(L2C, 2 * hi3);
    const int lo1 = max(0, 2 * lo2 - 6), hi1 = min(L1C, 2 * hi2);
    const int lox = max(0, 2 * lo1 - 6), hix = min(L0C, 2 * hi1);

    // ---- stage x tile into transposed rows (+ reflection margins) ----
    const float* xb = x + b * (L0C * 32) + c0;
    const int npair = (hix - lox) >> 1;
    for (int q = tid; q < npair; q += NT) {
        const int j = q << 1;
        const int t = lox + j;
        const float4 va = *reinterpret_cast<const float4*>(xb + t * 32);
        const float4 vb = *reinterpret_cast<const float4*>(xb + t * 32 + 32);
        const float av[4] = {va.x, va.y, va.z, va.w};
        const float bv[4] = {vb.x, vb.y, vb.z, vb.w};
#pragma unroll
        for (int hh = 0; hh < NCHB; ++hh)
            *reinterpret_cast<float2*>(bx + hh * LPX + 6 + j) =
                make_float2(av[hh], bv[hh]);
        if (lox == 0 && t < 6) {
#pragma unroll
            for (int hh = 0; hh < NCHB; ++hh) {
                bx[hh * LPX + 5 - t] = av[hh];
                if (t + 1 < 6) bx[hh * LPX + 4 - t] = bv[hh];
            }
        }
        if (hix == L0C && t + 1 >= L0C - 7) {
#pragma unroll
            for (int hh = 0; hh < NCHB; ++hh) {
                if (t >= L0C - 7) bx[hh * LPX + (2 * L0C - 1 - t) - lox + 6] = av[hh];
                bx[hh * LPX + (2 * L0C - 2 - t) - lox + 6] = bv[hh];
            }
        }
    }
    __syncthreads();

    if (tile == 0 || tile == 7)
        cascade<true>(bx, b2, cd1, cd2, cd3, cd4, ca4, out, sigB, tile,
                      c, slot, tid, lox, lo2, hi2, lo4, hi4);
    else
        cascade<false>(bx, b2, cd1, cd2, cd3, cd4, ca4, out, sigB, tile,
                       c, slot, tid, lox, lo2, hi2, lo4, hi4);
}

extern "C" void kernel_launch(void* const* d_in, const int* in_sizes, int n_in,
                              void* d_out, int out_size, void* d_ws, size_t ws_size,
                              hipStream_t stream) {
    (void)in_sizes; (void)n_in; (void)d_ws; (void)ws_size; (void)out_size;
    const float* x = (const float*)d_in[0];
    float* out = (float*)d_out;
    fused_dwt_kernel<<<dim3(4096), dim3(NT), 0, stream>>>(x, out);
}